// Round 3
// baseline (524.108 us; speedup 1.0000x reference)
//
#include <hip/hip_runtime.h>

#define MARGIN 0.3f
#define NEG_INF -1e9f

typedef __attribute__((ext_vector_type(4))) float f32x4;
typedef __attribute__((ext_vector_type(8))) short short8;
typedef __attribute__((ext_vector_type(4))) unsigned int u32x4;

// One wave per sample, 4 waves (samples) per block. No LDS, no barriers.
// Gram G = E*E^T via mfma_f32_16x16x32_bf16 (same fragment as A and B).
// Post-hoc normalization: sim[i][j] = G[i][j]*rn[i]*rn[j], rn = 1/max(sqrt(Gii),eps).
// C/D layout (gfx950, verified): col = lane&15, row = quad*4 + reg.
__global__ __launch_bounds__(256, 8) void cf_loss_kernel(
    const float* __restrict__ emb,    // [B,16,768] fp32
    const int*   __restrict__ labels, // [B,16]
    float* __restrict__ ws,           // [0..255] loss buckets, [256..511] count buckets
    int B)
{
    const int lane = threadIdx.x & 63;
    const int w    = threadIdx.x >> 6;
    const int s    = blockIdx.x * 4 + w;
    const bool active = (s < B);
    const int sc   = active ? s : 0;

    const int m    = lane & 15;   // column of C this lane holds / row of E it loads
    const int quad = lane >> 4;   // this lane's quad → holds rows 4*quad..4*quad+3

    // prefetch labels so the scalar-ish load overlaps the stream loop
    int lab = -1;
    if (lane < 16) lab = labels[sc * 16 + lane];

    // ---- Gram via MFMA, depth-1 software pipeline (2 loads in flight) ----
    f32x4 acc = {0.f, 0.f, 0.f, 0.f};
    const float* rowp = emb + ((size_t)sc * 16 + m) * 768 + quad * 8;

    f32x4 x0 = *(const f32x4*)(rowp);
    f32x4 y0 = *(const f32x4*)(rowp + 4);

    #pragma unroll 1
    for (int c = 0; c < 23; ++c) {
        f32x4 x1 = *(const f32x4*)(rowp + 32);   // prefetch next 32B
        f32x4 y1 = *(const f32x4*)(rowp + 36);
        union { short8 s8; u32x4 u4; } frag;
        frag.u4[0] = __builtin_amdgcn_perm(__float_as_uint(x0[1]), __float_as_uint(x0[0]), 0x07060302u);
        frag.u4[1] = __builtin_amdgcn_perm(__float_as_uint(x0[3]), __float_as_uint(x0[2]), 0x07060302u);
        frag.u4[2] = __builtin_amdgcn_perm(__float_as_uint(y0[1]), __float_as_uint(y0[0]), 0x07060302u);
        frag.u4[3] = __builtin_amdgcn_perm(__float_as_uint(y0[3]), __float_as_uint(y0[2]), 0x07060302u);
        acc = __builtin_amdgcn_mfma_f32_16x16x32_bf16(frag.s8, frag.s8, acc, 0, 0, 0);
        x0 = x1; y0 = y1;
        rowp += 32;
    }
    {   // last iteration (no prefetch)
        union { short8 s8; u32x4 u4; } frag;
        frag.u4[0] = __builtin_amdgcn_perm(__float_as_uint(x0[1]), __float_as_uint(x0[0]), 0x07060302u);
        frag.u4[1] = __builtin_amdgcn_perm(__float_as_uint(x0[3]), __float_as_uint(x0[2]), 0x07060302u);
        frag.u4[2] = __builtin_amdgcn_perm(__float_as_uint(y0[1]), __float_as_uint(y0[0]), 0x07060302u);
        frag.u4[3] = __builtin_amdgcn_perm(__float_as_uint(y0[3]), __float_as_uint(y0[2]), 0x07060302u);
        acc = __builtin_amdgcn_mfma_f32_16x16x32_bf16(frag.s8, frag.s8, acc, 0, 0, 0);
    }

    // ---- in-register epilogue (no LDS, no barriers) ----
    unsigned long long posmask = __ballot(lane < 16 && lab == 1);
    unsigned long long negmask = __ballot(lane < 16 && lab == 0);
    const bool valid = (posmask != 0ull) && (negmask != 0ull);

    // Gather diagonal G[m][m] for this lane's column m.
    // Diag d lives in lane (d>>2)*16 + d, register d&3.
    const int src = (m >> 2) * 16 + m;
    float d0 = __shfl(acc[0], src);
    float d1 = __shfl(acc[1], src);
    float d2 = __shfl(acc[2], src);
    float d3 = __shfl(acc[3], src);
    const int k = m & 3;
    float diag = (k == 0) ? d0 : (k == 1) ? d1 : (k == 2) ? d2 : d3;
    float rnm  = 1.0f / fmaxf(sqrtf(diag), 1e-12f);   // rn for this lane's column

    const bool isnegm = (negmask >> m) & 1ull;

    float contrib = 0.0f;
    #pragma unroll
    for (int r = 0; r < 4; ++r) {
        const int row = 4 * quad + r;
        // per-column scaled value = G[row][m] * rn[m]  (true sim up to rn[row] factor)
        float v = isnegm ? acc[r] * rnm : NEG_INF;
        // max over the 16 columns (lanes within this quad group)
        v = fmaxf(v, __shfl_xor(v, 1));
        v = fmaxf(v, __shfl_xor(v, 2));
        v = fmaxf(v, __shfl_xor(v, 4));
        v = fmaxf(v, __shfl_xor(v, 8));
        float rnrow = __shfl(rnm, row);               // lane 'row' (<16) has m==row
        float trip  = fmaxf(v * rnrow + MARGIN, 0.0f);
        bool  ispos = (posmask >> row) & 1ull;
        contrib += ispos ? trip : 0.0f;
    }
    // contrib is replicated across the 16 lanes of each quad; keep one copy
    if (m != 0) contrib = 0.0f;
    if (!active || !valid) contrib = 0.0f;
    contrib += __shfl_xor(contrib, 16);
    contrib += __shfl_xor(contrib, 32);   // lanes 0/16/32/48 now hold the sample sum

    if (lane == 0) {
        const int bucket = s & 255;
        atomicAdd(&ws[bucket], contrib);
        float cnt = (active && valid) ? (float)__popcll(posmask) : 0.0f;
        atomicAdd(&ws[256 + bucket], cnt);
    }
}

__global__ void cf_finalize_kernel(const float* __restrict__ ws,
                                   float* __restrict__ out)
{
    const int t = threadIdx.x;   // 64 threads
    float s = ws[t] + ws[t + 64] + ws[t + 128] + ws[t + 192];
    float c = ws[256 + t] + ws[256 + t + 64] + ws[256 + t + 128] + ws[256 + t + 192];
    #pragma unroll
    for (int o = 1; o < 64; o <<= 1) {
        s += __shfl_xor(s, o);
        c += __shfl_xor(c, o);
    }
    if (t == 0) out[0] = s / fmaxf(c, 1.0f);
}

extern "C" void kernel_launch(void* const* d_in, const int* in_sizes, int n_in,
                              void* d_out, int out_size, void* d_ws, size_t ws_size,
                              hipStream_t stream) {
    const float* emb    = (const float*)d_in[0];
    const int*   labels = (const int*)d_in[1];
    float* out = (float*)d_out;
    float* ws  = (float*)d_ws;

    const int B = in_sizes[0] / (16 * 768);   // 8192

    // ws is poisoned 0xAA before every launch — zero the 512 bucket floats.
    hipMemsetAsync(ws, 0, 512 * sizeof(float), stream);

    const int blocks = (B + 3) / 4;
    cf_loss_kernel<<<blocks, 256, 0, stream>>>(emb, labels, ws, B);
    cf_finalize_kernel<<<1, 64, 0, stream>>>(ws, out);
}